// Round 7
// baseline (643.911 us; speedup 1.0000x reference)
//
#include <hip/hip_runtime.h>

#define NN 50000
#define NE 400000
#define CNN 25000
#define NBINS 1024

// weight offsets
#define RL1ST 0            // l1s transposed: (192,64) col-contiguous
#define RL1VT 12288        // l1v transposed: (64,64)
#define RL2S  16384        // l2s original (160,32)
#define RL2V  21504        // l2v original (96,32)
#define WTOT  24576

#define SLUT_N ((NBINS+1)*256)
#define N_INTS (3*NN+1)

#define FULL_TOT_FL ((size_t)NN*256 + WTOT + SLUT_N + (size_t)NE*6 + N_INTS)
#define CH_TOT_FL   ((size_t)CNN*256 + WTOT + SLUT_N + (size_t)NE*6 + N_INTS)
#define WS_FULL_BYTES (FULL_TOT_FL*4ull)   // ~62.5 MB
#define WS_CH_BYTES   (CH_TOT_FL*4ull)     // ~36.9 MB (guaranteed: ws >= 54.5 MB)

#define S160 0.07905694150420949f
#define S96  0.10206207261596576f

__device__ __forceinline__ float sigf(float x){
  return __builtin_amdgcn_rcpf(1.0f + __expf(-x));
}
__device__ __forceinline__ float siluf(float x){ return x * sigf(x); }

// ---- weights: transpose l1s,l1v; copy l2s,l2v ----
__global__ __launch_bounds__(256) void convert_weights(
    const float* __restrict__ l1s, const float* __restrict__ l1v,
    const float* __restrict__ l2s, const float* __restrict__ l2v,
    float* __restrict__ wgt)
{
  int i = blockIdx.x*256 + threadIdx.x;
  if (i < 12288){ int o=i>>6, m=i&63; wgt[RL1ST + i] = l1s[m*192+o]; return; }
  if (i < 16384){ int t=i-12288; int o=t>>6, m=t&63; wgt[RL1VT + t] = l1v[m*64+o]; return; }
  if (i < 21504){ int t=i-16384; wgt[RL2S + t] = l2s[t]; return; }
  if (i < 24576){ int t=i-21504; wgt[RL2V + t] = l2v[t]; return; }
}

// ---- SLUT[bin][256]: scal(x) at bin edges, component-remapped ----
__global__ __launch_bounds__(128) void build_lut(
    const float* __restrict__ w1, const float* __restrict__ b1,
    const float* __restrict__ w2, const float* __restrict__ b2,
    const float* __restrict__ w3, const float* __restrict__ b3,
    float* __restrict__ slut)
{
  __shared__ float h1[64], h2[64], scal[128];
  int bin = blockIdx.x;
  float x = (float)bin / (float)NBINS;
  int t = threadIdx.x;
  if (t < 64) h1[t] = siluf(fmaf(x, w1[t], b1[t]));
  __syncthreads();
  if (t < 64){
    float a = b2[t];
    for (int k=0;k<64;k++) a = fmaf(h1[k], w2[k*64+t], a);
    h2[t] = siluf(a);
  }
  __syncthreads();
  {
    float a = b3[t];
    for (int k=0;k<64;k++) a = fmaf(h2[k], w3[k*128+t], a);
    scal[t] = a;
  }
  __syncthreads();
  for (int c=t; c<256; c+=128){
    int m=c>>3, q=c&7;
    int idx = (q==0)? m : (q==1)? (32+m) : (q<5)? (64+m) : (96+m);
    slut[(size_t)bin*256 + c] = scal[idx];
  }
}

// ================= CSR build =================
__global__ __launch_bounds__(256) void count_kernel(
    const int* __restrict__ rcv, int* __restrict__ cnt)
{
  int e = blockIdx.x*256 + threadIdx.x;
  if (e < NE) atomicAdd(&cnt[rcv[e]], 1);
}

__global__ __launch_bounds__(1024) void scan_kernel(
    const int* __restrict__ cnt, int* __restrict__ offs, int* __restrict__ curs)
{
  __shared__ int sdata[1024];
  int tid = threadIdx.x;
  const int CH = 49;
  int base = tid*CH;
  int s = 0;
  for (int i=0;i<CH;i++){ int idx=base+i; if (idx<NN) s += cnt[idx]; }
  sdata[tid] = s;
  __syncthreads();
  for (int off=1; off<1024; off<<=1){
    int t = 0;
    if (tid >= off) t = sdata[tid-off];
    __syncthreads();
    sdata[tid] += t;
    __syncthreads();
  }
  int run = sdata[tid] - s;
  for (int i=0;i<CH;i++){
    int idx = base+i;
    if (idx < NN){ offs[idx]=run; curs[idx]=run; run += cnt[idx]; }
  }
  if (tid == 1023) offs[NN] = run;
}

// scatter + pre-gather edge payload into CSR order
__global__ __launch_bounds__(256) void scatter_kernel(
    const int* __restrict__ rcv, const int* __restrict__ snd,
    const float* __restrict__ nrm, const float* __restrict__ sh,
    int* __restrict__ curs,
    float4* __restrict__ esh, float* __restrict__ ex, int* __restrict__ esnd)
{
  int e = blockIdx.x*256 + threadIdx.x;
  if (e >= NE) return;
  int pos = atomicAdd(&curs[rcv[e]], 1);
  esh[pos]  = *(const float4*)(sh + 4*e);
  ex[pos]   = nrm[e];
  esnd[pos] = snd[e];
}

// ================= Edge+aggregate: wave per node, lane per 4 comps =========
__device__ __forceinline__ void edge_step(
    int p, const float4* __restrict__ esh, const float* __restrict__ ex,
    const int* __restrict__ esnd,
    const float* __restrict__ ns, const float* __restrict__ nv,
    const float4* __restrict__ slut4, int m, int odd, int lane,
    float& a0, float& a1, float& a2, float& a3)
{
  int s    = esnd[p];
  float x  = ex[p];
  float4 y = esh[p];
  float f = x * (float)NBINS;
  f = fminf(fmaxf(f, 0.0f), (float)NBINS - 0.001f);
  int bin = (int)f;
  float tt = f - (float)bin;
  float4 L0 = slut4[(size_t)bin*64 + lane];
  float4 L1 = slut4[(size_t)(bin+1)*64 + lane];
  float se = ns[(size_t)s*32 + m];
  const float* vp = nv + (size_t)s*96 + 3*m;
  float v0 = vp[0], v1 = vp[1], v2 = vp[2];
  float sc0 = fmaf(tt, L1.x-L0.x, L0.x);
  float sc1 = fmaf(tt, L1.y-L0.y, L0.y);
  float sc2 = fmaf(tt, L1.z-L0.z, L0.z);
  float sc3 = fmaf(tt, L1.w-L0.w, L0.w);
  const float inv_sqrt3 = 0.57735026918962576f;
  float A0,A1,A2,A3;
  if (!odd){
    float dot = fmaf(y.w, v2, fmaf(y.z, v1, y.y*v0));
    A0 = y.x*se; A1 = dot*inv_sqrt3; A2 = y.x*v0; A3 = y.x*v1;
  } else {
    A0 = y.x*v2; A1 = y.y*se; A2 = y.z*se; A3 = y.w*se;
  }
  a0 = fmaf(A0, sc0, a0);
  a1 = fmaf(A1, sc1, a1);
  a2 = fmaf(A2, sc2, a2);
  a3 = fmaf(A3, sc3, a3);
}

__global__ __launch_bounds__(256) void edge_agg_kernel(
    const float* __restrict__ ns, const float* __restrict__ nv,
    const float4* __restrict__ esh, const float* __restrict__ ex,
    const int* __restrict__ esnd,
    const int* __restrict__ offs, const float* __restrict__ slut,
    float* __restrict__ agg, int cn0, int cnn)
{
  int wave = threadIdx.x >> 6;
  int lane = threadIdx.x & 63;
  int nl = blockIdx.x*4 + wave;
  if (nl >= cnn) return;
  int n = cn0 + nl;
  int m = lane >> 1;
  int odd = lane & 1;
  int p0 = offs[n], p1 = offs[n+1];
  const float4* slut4 = (const float4*)slut;
  float a0=0.f, a1=0.f, a2=0.f, a3=0.f;
  float b0=0.f, b1=0.f, b2=0.f, b3=0.f;

  int p = p0;
  for (; p+1 < p1; p += 2){
    edge_step(p,   esh, ex, esnd, ns, nv, slut4, m, odd, lane, a0,a1,a2,a3);
    edge_step(p+1, esh, ex, esnd, ns, nv, slut4, m, odd, lane, b0,b1,b2,b3);
  }
  if (p < p1)
    edge_step(p, esh, ex, esnd, ns, nv, slut4, m, odd, lane, a0,a1,a2,a3);

  a0 += b0; a1 += b1; a2 += b2; a3 += b3;
  int deg = p1 - p0;
  float inv = (deg > 0) ? __builtin_amdgcn_rcpf((float)deg) : 1.0f;
  float4 o; o.x=a0*inv; o.y=a1*inv; o.z=a2*inv; o.w=a3*inv;
  *(float4*)(agg + (size_t)nl*256 + 4*lane) = o;
}

// ================= Node phase v3: LDS slab + lane-pair split-K =============
// 32 nodes/block. lane = (half<<5)|node. Half h covers K-rows h*32..h*32+31.
// slab row c-mapping: c=m*8+q, q0->s(m), q1->s(32+m), q2..4->v(m,k), q5..7->v(32+m,k)
__global__ __launch_bounds__(256,3) void node_kernel(
    const float* __restrict__ ns, const float* __restrict__ nv,
    const float* __restrict__ wgt, const float* __restrict__ agg,
    int cn0, int cnn, float* __restrict__ out)
{
  __shared__ float slab[32*257];     // 32.9 KB
  __shared__ float sgate[64*32];     // 8 KB
  int tid = threadIdx.x;
  int nb0 = blockIdx.x*32;
  int ncount = cnn - nb0; if (ncount > 32) ncount = 32;
  for (int i=tid; i<ncount*256; i+=256){
    int nl=i>>8, c=i&255;
    slab[nl*257+c] = agg[(size_t)(nb0+nl)*256+c];
  }
  __syncthreads();

  int lane = tid & 63, role = tid >> 6;
  int node = lane & 31;
  int half = lane >> 5;
  bool valid = (node < ncount);
  int n = cn0 + nb0 + node;
  const float* srow = slab + node*257;
  const float* l1sT = wgt + RL1ST;

  float aggs[32];
  if (valid){
    #pragma unroll
    for (int g=0;g<32;g++) aggs[g] = srow[8*g + half];
    // Phase A: gates (64 cols split 16/role), split-K over halves
    for (int t=0;t<16;t++){
      int o = role*16 + t;
      const float4* col = (const float4*)(l1sT + (size_t)(128+o)*64) + half*8;
      float d0=0,d1=0,d2=0,d3=0;
      #pragma unroll
      for (int j=0;j<8;j++){
        float4 c4 = col[j];
        d0 = fmaf(aggs[4*j+0], c4.x, d0);
        d1 = fmaf(aggs[4*j+1], c4.y, d1);
        d2 = fmaf(aggs[4*j+2], c4.z, d2);
        d3 = fmaf(aggs[4*j+3], c4.w, d3);
      }
      float d = (d0+d1)+(d2+d3);
      d += __shfl_xor(d, 32, 64);
      sgate[o*32 + node] = sigf(d*0.125f);
    }
  }
  __syncthreads();
  if (!valid) return;

  if (role == 0){
    float oacc[16];
    #pragma unroll
    for (int j=0;j<16;j++) oacc[j]=0.0f;
    const float* l2s = wgt + RL2S;
    for (int o=0;o<128;o++){
      const float4* col = (const float4*)(l1sT + (size_t)o*64) + half*8;
      float d0=0,d1=0,d2=0,d3=0;
      #pragma unroll
      for (int j=0;j<8;j++){
        float4 c4 = col[j];
        d0 = fmaf(aggs[4*j+0], c4.x, d0);
        d1 = fmaf(aggs[4*j+1], c4.y, d1);
        d2 = fmaf(aggs[4*j+2], c4.z, d2);
        d3 = fmaf(aggs[4*j+3], c4.w, d3);
      }
      float d = (d0+d1)+(d2+d3);
      d += __shfl_xor(d, 32, 64);
      float act = siluf(d*0.125f);
      const float4* row = (const float4*)(l2s + (size_t)o*32) + half*4;
      #pragma unroll
      for (int j=0;j<4;j++){
        float4 w = row[j];
        oacc[4*j+0] = fmaf(act, w.x, oacc[4*j+0]);
        oacc[4*j+1] = fmaf(act, w.y, oacc[4*j+1]);
        oacc[4*j+2] = fmaf(act, w.z, oacc[4*j+2]);
        oacc[4*j+3] = fmaf(act, w.w, oacc[4*j+3]);
      }
    }
    const float4* sp = (const float4*)(ns + (size_t)n*32);
    #pragma unroll
    for (int q4=0;q4<8;q4++){
      float4 v = sp[q4];
      float vv[4] = {v.x, v.y, v.z, v.w};
      #pragma unroll
      for (int u=0;u<4;u++){
        float a = vv[u];
        const float4* row = (const float4*)(wgt + RL2S + (size_t)(128+q4*4+u)*32) + half*4;
        #pragma unroll
        for (int j=0;j<4;j++){
          float4 w = row[j];
          oacc[4*j+0] = fmaf(a, w.x, oacc[4*j+0]);
          oacc[4*j+1] = fmaf(a, w.y, oacc[4*j+1]);
          oacc[4*j+2] = fmaf(a, w.z, oacc[4*j+2]);
          oacc[4*j+3] = fmaf(a, w.w, oacc[4*j+3]);
        }
      }
    }
    float* op = out + (size_t)n*128 + half*16;
    #pragma unroll
    for (int j=0;j<16;j++) op[j] = oacc[j]*S160;
  } else {
    int k = role - 1;
    float aggv[32];
    #pragma unroll
    for (int g=0;g<32;g++) aggv[g] = srow[8*g + 2 + half*3 + k];
    float oacc[16];
    #pragma unroll
    for (int j=0;j<16;j++) oacc[j]=0.0f;
    const float* l1vT = wgt + RL1VT;
    const float* l2v  = wgt + RL2V;
    for (int o=0;o<64;o++){
      const float4* col = (const float4*)(l1vT + (size_t)o*64) + half*8;
      float d0=0,d1=0,d2=0,d3=0;
      #pragma unroll
      for (int j=0;j<8;j++){
        float4 c4 = col[j];
        d0 = fmaf(aggv[4*j+0], c4.x, d0);
        d1 = fmaf(aggv[4*j+1], c4.y, d1);
        d2 = fmaf(aggv[4*j+2], c4.z, d2);
        d3 = fmaf(aggv[4*j+3], c4.w, d3);
      }
      float d = (d0+d1)+(d2+d3);
      d += __shfl_xor(d, 32, 64);
      float gv = (d*0.125f) * sgate[o*32 + node];
      const float4* row = (const float4*)(l2v + (size_t)o*32) + half*4;
      #pragma unroll
      for (int j=0;j<4;j++){
        float4 w = row[j];
        oacc[4*j+0] = fmaf(gv, w.x, oacc[4*j+0]);
        oacc[4*j+1] = fmaf(gv, w.y, oacc[4*j+1]);
        oacc[4*j+2] = fmaf(gv, w.z, oacc[4*j+2]);
        oacc[4*j+3] = fmaf(gv, w.w, oacc[4*j+3]);
      }
    }
    const float* vp = nv + (size_t)n*96 + k;
    #pragma unroll 4
    for (int q=0;q<32;q++){
      float a = vp[3*q];
      const float4* row = (const float4*)(l2v + (size_t)(64+q)*32) + half*4;
      #pragma unroll
      for (int j=0;j<4;j++){
        float4 w = row[j];
        oacc[4*j+0] = fmaf(a, w.x, oacc[4*j+0]);
        oacc[4*j+1] = fmaf(a, w.y, oacc[4*j+1]);
        oacc[4*j+2] = fmaf(a, w.z, oacc[4*j+2]);
        oacc[4*j+3] = fmaf(a, w.w, oacc[4*j+3]);
      }
    }
    float* op = out + (size_t)n*128 + 32 + k + half*48;  // 3*(half*16)
    #pragma unroll
    for (int j=0;j<16;j++) op[3*j] = oacc[j]*S96;
  }
}

extern "C" void kernel_launch(void* const* d_in, const int* in_sizes, int n_in,
                              void* d_out, int out_size, void* d_ws, size_t ws_size,
                              hipStream_t stream) {
  const float* node_scalars = (const float*)d_in[0];
  const float* node_vectors = (const float*)d_in[1];
  const float* sh           = (const float*)d_in[2];
  const float* norm         = (const float*)d_in[3];
  const float* w1  = (const float*)d_in[4];
  const float* b1  = (const float*)d_in[5];
  const float* w2  = (const float*)d_in[6];
  const float* b2  = (const float*)d_in[7];
  const float* w3  = (const float*)d_in[8];
  const float* b3  = (const float*)d_in[9];
  const float* l1s = (const float*)d_in[10];
  const float* l1v = (const float*)d_in[11];
  const float* l2s = (const float*)d_in[12];
  const float* l2v = (const float*)d_in[13];
  const int* snd = (const int*)d_in[14];
  const int* rcv = (const int*)d_in[15];
  float* ws = (float*)d_ws;
  float* out = (float*)d_out;

  if (ws_size < WS_CH_BYTES) return;
  bool full = (ws_size >= WS_FULL_BYTES);
  size_t aggfl = full ? (size_t)NN*256 : (size_t)CNN*256;

  float* agg  = ws;
  float* wgt  = ws + aggfl;
  float* slut = wgt + WTOT;
  float4* esh = (float4*)(slut + SLUT_N);
  float* ex   = (float*)esh + (size_t)NE*4;
  int* esnd   = (int*)(ex + NE);
  int* ib     = esnd + NE;
  int* cnt  = ib;
  int* offs = ib + NN;
  int* curs = ib + 2*NN + 1;

  hipMemsetAsync(cnt, 0, NN*sizeof(int), stream);

  convert_weights<<<(WTOT+255)/256, 256, 0, stream>>>(l1s, l1v, l2s, l2v, wgt);
  build_lut<<<NBINS+1, 128, 0, stream>>>(w1,b1,w2,b2,w3,b3, slut);

  count_kernel<<<(NE+255)/256, 256, 0, stream>>>(rcv, cnt);
  scan_kernel<<<1, 1024, 0, stream>>>(cnt, offs, curs);
  scatter_kernel<<<(NE+255)/256, 256, 0, stream>>>(
      rcv, snd, norm, sh, curs, esh, ex, esnd);

  int nchunks = full ? 1 : 2;
  int csize   = full ? NN : CNN;
  for (int ch = 0; ch < nchunks; ch++){
    int cn0 = ch * csize;
    edge_agg_kernel<<<(csize+3)/4, 256, 0, stream>>>(
        node_scalars, node_vectors, esh, ex, esnd, offs, slut,
        agg, cn0, csize);
    node_kernel<<<(csize+31)/32, 256, 0, stream>>>(
        node_scalars, node_vectors, wgt, agg, cn0, csize, out);
  }
}